// Round 9
// baseline (408.939 us; speedup 1.0000x reference)
//
#include <hip/hip_runtime.h>
#include <hip/hip_bf16.h>

typedef unsigned char uchar;
typedef __attribute__((ext_vector_type(8))) short bf16x8;
typedef __attribute__((ext_vector_type(4))) float f32x4;

__device__ __forceinline__ unsigned short f2bf(float f) {
  union { float f; unsigned int u; } v; v.f = f;
  unsigned int u = v.u + 0x7fffu + ((v.u >> 16) & 1u);
  return (unsigned short)(u >> 16);
}

__device__ __forceinline__ void async_cp16(void* lds, const void* g) {
  __builtin_amdgcn_global_load_lds(
      (const __attribute__((address_space(1))) unsigned int*)g,
      (__attribute__((address_space(3))) unsigned int*)lds, 16, 0, 0);
}

// ---------------- K1: patch bins px,py per (b,n), packed u16 ----------------
__global__ void pxpy_kernel(const float* __restrict__ boxes, const int* __restrict__ isz,
                            unsigned short* __restrict__ ppk) {
  int idx = blockIdx.x * 256 + threadIdx.x;  // < 8192
  int b = idx >> 9;
  float w = (float)isz[b * 4 + 0];
  float h = (float)isz[b * 4 + 1];
  float b0 = boxes[idx * 4 + 0] * w;
  float b1 = boxes[idx * 4 + 1] * h;
  float b2 = boxes[idx * 4 + 2] * w;
  float b3 = boxes[idx * 4 + 3] * h;
  float spw = floorf(w / 11.0f);
  float sph = floorf(h / 11.0f);
  float cx = floorf((b0 + b2) * 0.5f);
  float cy = floorf((b1 + b3) * 0.5f);
  int pxi = 0, pyi = 0;
  bool fx = false, fy = false;
  for (int j = 0; j < 11; ++j) {
    float jf = (float)j;
    if (!fx && jf * spw <= cx && cx <= (jf + 1.0f) * spw) { pxi = j; fx = true; }
    if (!fy && jf * sph <= cy && cy <= (jf + 1.0f) * sph) { pyi = j; fy = true; }
  }
  ppk[idx] = (unsigned short)(pxi | (pyi << 8));
}

// ---------------- K3: LayerNorm -> bf16 ----------------
__global__ __launch_bounds__(256) void ln_kernel(const float* __restrict__ f,
                                                 const float* __restrict__ gamma,
                                                 const float* __restrict__ beta,
                                                 unsigned short* __restrict__ x) {
  const int r = blockIdx.x;
  const int t = threadIdx.x;
  const float* row = f + (size_t)r * 768;
  float e0 = row[t], e1 = row[t + 256], e2 = row[t + 512];
  float s = e0 + e1 + e2;
#pragma unroll
  for (int off = 32; off > 0; off >>= 1) s += __shfl_down(s, off);
  __shared__ float red[4];
  const int wid = t >> 6;
  if ((t & 63) == 0) red[wid] = s;
  __syncthreads();
  float mean = (red[0] + red[1] + red[2] + red[3]) * (1.0f / 768.0f);
  __syncthreads();
  float d0 = e0 - mean, d1 = e1 - mean, d2 = e2 - mean;
  float v = d0 * d0 + d1 * d1 + d2 * d2;
#pragma unroll
  for (int off = 32; off > 0; off >>= 1) v += __shfl_down(v, off);
  if ((t & 63) == 0) red[wid] = v;
  __syncthreads();
  float var = (red[0] + red[1] + red[2] + red[3]) * (1.0f / 768.0f);
  float rs = rsqrtf(var + 1e-5f);
  x[(size_t)r * 768 + t]       = f2bf(d0 * rs * gamma[t] + beta[t]);
  x[(size_t)r * 768 + t + 256] = f2bf(d1 * rs * gamma[t + 256] + beta[t + 256]);
  x[(size_t)r * 768 + t + 512] = f2bf(d2 * rs * gamma[t + 512] + beta[t + 512]);
}

// ---------------- K4: weight prep (bf16 conversion + concat) ----------------
__global__ void wprep_kernel(const float* __restrict__ Wq, const float* __restrict__ Wk,
                             const float* __restrict__ Wv, const float* __restrict__ Wo,
                             const float* __restrict__ bq, const float* __restrict__ bk,
                             const float* __restrict__ bv,
                             unsigned short* __restrict__ wcat, unsigned short* __restrict__ wo,
                             float* __restrict__ bcat) {
  int idx = blockIdx.x * 256 + threadIdx.x;  // < 2359296
  if (idx < 1769472) {
    int n = idx / 768, k = idx % 768;
    float v = (n < 768) ? Wq[n * 768 + k]
            : (n < 1536) ? Wk[(n - 768) * 768 + k]
                         : Wv[(n - 1536) * 768 + k];
    wcat[idx] = f2bf(v);
  } else {
    int j = idx - 1769472;
    wo[j] = f2bf(Wo[j]);
  }
  if (idx < 2304)
    bcat[idx] = (idx < 768) ? bq[idx] : (idx < 1536) ? bk[idx - 768] : bv[idx - 1536];
}

// ---------------- K5/K7: GEMM  C[m,n] = sum_k A[m,k]*Bt[n,k] + bias[n] ----------------
// 128x128 tile, BK=32, 256 threads (2x2 waves of 64x64).
// 2-phase double-buffered global_load_lds staging (proven +11us in round 5). Round-6 version.
template <bool OUTF32>
__global__ __launch_bounds__(256) void gemm_bt(const unsigned short* __restrict__ A,
                                               const unsigned short* __restrict__ Bt,
                                               const float* __restrict__ bias,
                                               void* __restrict__ Cout, int K, int ldc) {
  __shared__ unsigned short a_lds[2][128 * 32];
  __shared__ unsigned short b_lds[2][128 * 32];
  const int m0 = blockIdx.x * 128, n0 = blockIdx.y * 128;
  const int tid = threadIdx.x;
  const int lane = tid & 63, wid = tid >> 6;
  const int ln = lane & 15, quad = lane >> 4;
  const int wm = (wid & 1) * 64, wn = (wid >> 1) * 64;
  f32x4 acc[16] = {};
  const int nk = K >> 5;
#pragma unroll
  for (int rep = 0; rep < 2; ++rep) {
    int c = rep * 256 + tid;
    int row = c >> 2, e0 = (c & 3) << 3;
    async_cp16(&a_lds[0][c * 8], A + (size_t)(m0 + row) * K + e0);
    async_cp16(&b_lds[0][c * 8], Bt + (size_t)(n0 + row) * K + e0);
  }
  __syncthreads();
  for (int kc = 0; kc < nk; ++kc) {
    const int cur = kc & 1;
    if (kc + 1 < nk) {
      const int k0 = (kc + 1) << 5;
#pragma unroll
      for (int rep = 0; rep < 2; ++rep) {
        int c = rep * 256 + tid;
        int row = c >> 2, e0 = (c & 3) << 3;
        async_cp16(&a_lds[cur ^ 1][c * 8], A + (size_t)(m0 + row) * K + k0 + e0);
        async_cp16(&b_lds[cur ^ 1][c * 8], Bt + (size_t)(n0 + row) * K + k0 + e0);
      }
    }
    bf16x8 af[4], bfr[4];
#pragma unroll
    for (int i = 0; i < 4; ++i)
      af[i] = *(const bf16x8*)&a_lds[cur][(wm + i * 16 + ln) * 32 + quad * 8];
#pragma unroll
    for (int j = 0; j < 4; ++j)
      bfr[j] = *(const bf16x8*)&b_lds[cur][(wn + j * 16 + ln) * 32 + quad * 8];
#pragma unroll
    for (int i = 0; i < 4; ++i)
#pragma unroll
      for (int j = 0; j < 4; ++j)
        acc[i * 4 + j] = __builtin_amdgcn_mfma_f32_16x16x32_bf16(af[i], bfr[j], acc[i * 4 + j], 0, 0, 0);
    __syncthreads();
  }
#pragma unroll
  for (int i = 0; i < 4; ++i)
#pragma unroll
    for (int j = 0; j < 4; ++j)
#pragma unroll
      for (int r = 0; r < 4; ++r) {
        int rr = m0 + wm + i * 16 + quad * 4 + r;
        int cc = n0 + wn + j * 16 + ln;
        float v = acc[i * 4 + j][r] + bias[cc];
        if (OUTF32) ((float*)Cout)[(size_t)rr * ldc + cc] = v;
        else ((unsigned short*)Cout)[(size_t)rr * ldc + cc] = f2bf(v);
      }
}

// ---------------- K6: fused attention (round-9: occupancy push) ----------------
// scores = softmax(q k^T / 8 + dist_bias) -> att (f32), out_h = scores @ v -> attnout (bf16).
// One block per (b, h, 64-row q tile); 4 waves each own 16 q-rows x 512 cols.
// Goal: VGPR 220 -> <=170 so 3 waves/SIMD instead of 2 (kernel is ~90% latency stall;
// MFMA work alone is ~5us of ~110us). Three coordinated parts:
//  1. Q/K staged via global_load_lds DIRECT into linear stride-64 LDS (kills 16 kr
//     prefetch VGPRs + ds_writes). Both-sides swizzle (#21): source col-group g^(row&7),
//     read col-group cg^(ln&7). 2-phase issue-ahead like the GEMM.
//  2. After softmax, P packed to bf16 pairs (p01/p23, 64 u32) -> the 128-reg f32 acc
//     dies before PV. Same f2bf rounding -> bit-identical att/attnout.
//  3. att f32 stores as a burst before packing (acc must die); stores drain under PV.
// PV keeps round-6's reg-staged V + stride-72 swizzled scatter (transpose).
// No XCD swizzle (round-8 A/B: +6us, disproven).
// Rule #20: all acc/p indexing static (round-4: dynamic index => spill, 4x slowdown).
__global__ __launch_bounds__(256) void attn_fused(const unsigned short* __restrict__ qkv,
                                                  const unsigned short* __restrict__ ppk,
                                                  const float* __restrict__ dist_emb,
                                                  float* __restrict__ att,
                                                  unsigned short* __restrict__ attnout) {
  const int bidx = blockIdx.x;
  const int qt = bidx & 7;
  const int h = (bidx >> 3) % 12;
  const int b = bidx / 96;
  __shared__ unsigned short qs[64 * 72];     // Q (stride 64, gload_lds) then P rows (stride 72)
  __shared__ unsigned short ks[2][64 * 72];  // K chunks (stride 64) then V^T chunks (stride 72)
  __shared__ float lut[448];
  __shared__ unsigned short pklds[512];
  const int tid = threadIdx.x;
  const int lane = tid & 63, wid = tid >> 6;
  const int ln = lane & 15, quad = lane >> 4;

  // staging coords: c in {tid, 256+tid}; row=c>>3, g=c&7; source col-group pre-swizzled
  const int c0 = tid, c1 = 256 + tid;
  const int r0 = c0 >> 3, g0 = c0 & 7;
  const int r1 = c1 >> 3, g1 = c1 & 7;
  const int sc0 = (g0 ^ (r0 & 7)) * 8;
  const int sc1 = (g1 ^ (r1 & 7)) * 8;
  const unsigned short* qg0 = qkv + (size_t)(b * 512 + qt * 64 + r0) * 2304 + h * 64 + sc0;
  const unsigned short* qg1 = qkv + (size_t)(b * 512 + qt * 64 + r1) * 2304 + h * 64 + sc1;
  const unsigned short* kg0 = qkv + (size_t)(b * 512 + r0) * 2304 + 768 + h * 64 + sc0;
  const unsigned short* kg1 = qkv + (size_t)(b * 512 + r1) * 2304 + 768 + h * 64 + sc1;
  // issue Q + K0 (direct to LDS, no regs)
  async_cp16(&qs[c0 * 8], qg0);
  async_cp16(&qs[c1 * 8], qg1);
  async_cp16(&ks[0][c0 * 8], kg0);
  async_cp16(&ks[0][c1 * 8], kg1);

  // bias LUT + packed (px,py)
  for (int t = tid; t < 441; t += 256) {
    int dx = t / 21 - 10, dy = t % 21 - 10;
    int bin = (int)(sqrtf((float)(dx * dx + dy * dy)) * 2.0f);
    lut[t] = dist_emb[bin * 12 + h];
  }
  if (tid < 64)
    *(uint4*)&pklds[tid * 8] = *(const uint4*)(ppk + (size_t)b * 512 + tid * 8);
  __syncthreads();  // drains gload_lds (vmcnt0 before barrier): Q+K0+lut+pk visible

  // a-frags from swizzled linear Q: want Q[arow][cg] -> LDS group cg^(arow&7); arow&7==ln&7
  const int arow = wid * 16 + ln;
  const int rs8 = (ln & 7);
  bf16x8 a0 = *(const bf16x8*)&qs[arow * 64 + ((quad ^ rs8) * 8)];
  bf16x8 a1 = *(const bf16x8*)&qs[arow * 64 + (((quad + 4) ^ rs8) * 8)];

  f32x4 acc[32] = {};
  const size_t kstep = (size_t)64 * 2304;
#pragma unroll
  for (int kc = 0; kc < 8; ++kc) {
    if (kc < 7) {  // issue next chunk into the other buffer (readers passed prior barrier)
      async_cp16(&ks[(kc + 1) & 1][c0 * 8], kg0 + (size_t)(kc + 1) * kstep);
      async_cp16(&ks[(kc + 1) & 1][c1 * 8], kg1 + (size_t)(kc + 1) * kstep);
    }
    const unsigned short* cur = ks[kc & 1];
    __builtin_amdgcn_s_setprio(1);
#pragma unroll
    for (int t = 0; t < 4; ++t) {
      const int brow = t * 16 + ln;  // brow&7 == ln&7
      bf16x8 b0 = *(const bf16x8*)&cur[brow * 64 + ((quad ^ rs8) * 8)];
      bf16x8 b1 = *(const bf16x8*)&cur[brow * 64 + (((quad + 4) ^ rs8) * 8)];
      acc[kc * 4 + t] = __builtin_amdgcn_mfma_f32_16x16x32_bf16(a0, b0, acc[kc * 4 + t], 0, 0, 0);
      acc[kc * 4 + t] = __builtin_amdgcn_mfma_f32_16x16x32_bf16(a1, b1, acc[kc * 4 + t], 0, 0, 0);
    }
    __builtin_amdgcn_s_setprio(0);
    if (kc < 7) __syncthreads();  // drains issued loads; next buffer ready
  }

  // V prefetch to regs (transpose scatter needs reg path); latency hides under softmax
  const int si = tid >> 3, se = (tid & 7) * 8;
  const unsigned short* vbase = qkv + (size_t)(b * 512) * 2304 + 1536 + h * 64 + se;
  uint4 vr0 = *(const uint4*)(vbase + (size_t)si * 2304);
  uint4 vr1 = *(const uint4*)(vbase + (size_t)(si + 32) * 2304);

  // bias + softmax (round-6 LUT path). C-layout: lane rows quad*4+r, col=16*tile+ln
  const int brow0 = qt * 64 + wid * 16 + quad * 4;
  int cr[4];
#pragma unroll
  for (int r = 0; r < 4; ++r) {
    int pq = pklds[brow0 + r];
    cr[r] = 220 - (pq & 255) * 21 - (pq >> 8);
  }
#pragma unroll
  for (int i = 0; i < 32; ++i) {
    int col = (i >> 2) * 64 + (i & 3) * 16 + ln;
    int pk = pklds[col];
    int base = (pk & 255) * 21 + (pk >> 8);
#pragma unroll
    for (int r = 0; r < 4; ++r) {
      acc[i][r] = acc[i][r] * 0.125f + lut[base + cr[r]];
    }
  }
  float inv[4];
#pragma unroll
  for (int r = 0; r < 4; ++r) {
    float m = -1e30f;
#pragma unroll
    for (int i = 0; i < 32; ++i) m = fmaxf(m, acc[i][r]);
    m = fmaxf(m, __shfl_xor(m, 1));
    m = fmaxf(m, __shfl_xor(m, 2));
    m = fmaxf(m, __shfl_xor(m, 4));
    m = fmaxf(m, __shfl_xor(m, 8));
    float s = 0.f;
#pragma unroll
    for (int i = 0; i < 32; ++i) { float p = __expf(acc[i][r] - m); acc[i][r] = p; s += p; }
    s += __shfl_xor(s, 1); s += __shfl_xor(s, 2); s += __shfl_xor(s, 4); s += __shfl_xor(s, 8);
    inv[r] = 1.0f / s;
  }
#pragma unroll
  for (int i = 0; i < 32; ++i)
#pragma unroll
    for (int r = 0; r < 4; ++r) acc[i][r] *= inv[r];

  // att store burst (async stores drain under PV), then pack P -> bf16 (acc dies)
  float* ob = att + (size_t)((b * 12 + h) * 512) * 512;
#pragma unroll
  for (int i = 0; i < 32; ++i) {
    int col = (i >> 2) * 64 + (i & 3) * 16 + ln;
#pragma unroll
    for (int r = 0; r < 4; ++r)
      ob[(size_t)(brow0 + r) * 512 + col] = acc[i][r];
  }
  unsigned int p01[32], p23[32];
#pragma unroll
  for (int i = 0; i < 32; ++i) {
    p01[i] = (unsigned int)f2bf(acc[i][0]) | ((unsigned int)f2bf(acc[i][1]) << 16);
    p23[i] = (unsigned int)f2bf(acc[i][2]) | ((unsigned int)f2bf(acc[i][3]) << 16);
  }

  // scatter V0 -> ks[0] (stride 72 + XOR swizzle; ks[0] last read at kc=6 barrier)
  {
    const unsigned short* xs = (const unsigned short*)&vr0;
#pragma unroll
    for (int j = 0; j < 8; ++j) {
      int d = se + j;
      ks[0][d * 72 + (si ^ (((d >> 3) & 7) << 3))] = xs[j];
    }
    xs = (const unsigned short*)&vr1;
#pragma unroll
    for (int j = 0; j < 8; ++j) {
      int d = se + j;
      ks[0][d * 72 + ((si + 32) ^ (((d >> 3) & 7) << 3))] = xs[j];
    }
  }
  __syncthreads();  // V0 visible
  f32x4 acc_o[4] = {};
  const int prow0 = wid * 16 + quad * 4;
  const int psw = ((wid * 4 + quad) & 7) << 3;  // ((row>>2)&7)<<3, constant for rows prow0..+3
#pragma unroll
  for (int kc = 0; kc < 8; ++kc) {
    const unsigned short* cur = ks[kc & 1];
    if (kc < 7) {
      vr0 = *(const uint4*)(vbase + (size_t)((kc + 1) * 64 + si) * 2304);
      vr1 = *(const uint4*)(vbase + (size_t)((kc + 1) * 64 + si + 32) * 2304);
    }
    // P drop from packed regs: wave-private rows, swizzled cols; no barrier needed
#pragma unroll
    for (int t = 0; t < 4; ++t) {
      int col = (t * 16 + ln) ^ psw;
      unsigned int a01 = p01[kc * 4 + t];
      unsigned int a23 = p23[kc * 4 + t];
      qs[(prow0 + 0) * 72 + col] = (unsigned short)a01;
      qs[(prow0 + 1) * 72 + col] = (unsigned short)(a01 >> 16);
      qs[(prow0 + 2) * 72 + col] = (unsigned short)a23;
      qs[(prow0 + 3) * 72 + col] = (unsigned short)(a23 >> 16);
    }
    __builtin_amdgcn_s_setprio(1);
#pragma unroll
    for (int kk = 0; kk < 2; ++kk) {
      int prow = wid * 16 + ln;
      int pcol = (kk * 32 + quad * 8) ^ (((prow >> 2) & 7) << 3);
      bf16x8 af = *(const bf16x8*)&qs[prow * 72 + pcol];
#pragma unroll
      for (int ct = 0; ct < 4; ++ct) {
        int d = ct * 16 + ln;
        int vcol = (kk * 32 + quad * 8) ^ (((d >> 3) & 7) << 3);
        bf16x8 bg = *(const bf16x8*)&cur[d * 72 + vcol];
        acc_o[ct] = __builtin_amdgcn_mfma_f32_16x16x32_bf16(af, bg, acc_o[ct], 0, 0, 0);
      }
    }
    __builtin_amdgcn_s_setprio(0);
    if (kc < 7) {
      unsigned short* nxt = ks[(kc + 1) & 1];
      const unsigned short* xs = (const unsigned short*)&vr0;
#pragma unroll
      for (int j = 0; j < 8; ++j) {
        int d = se + j;
        nxt[d * 72 + (si ^ (((d >> 3) & 7) << 3))] = xs[j];
      }
      xs = (const unsigned short*)&vr1;
#pragma unroll
      for (int j = 0; j < 8; ++j) {
        int d = se + j;
        nxt[d * 72 + ((si + 32) ^ (((d >> 3) & 7) << 3))] = xs[j];
      }
      __syncthreads();
    }
  }
#pragma unroll
  for (int ct = 0; ct < 4; ++ct)
#pragma unroll
    for (int r = 0; r < 4; ++r) {
      int m = b * 512 + qt * 64 + wid * 16 + quad * 4 + r;
      int cc = h * 64 + ct * 16 + ln;
      attnout[(size_t)m * 768 + cc] = f2bf(acc_o[ct][r]);
    }
}

extern "C" void kernel_launch(void* const* d_in, const int* in_sizes, int n_in,
                              void* d_out, int out_size, void* d_ws, size_t ws_size,
                              hipStream_t stream) {
  const float* features = (const float*)d_in[0];
  const float* boxes    = (const float*)d_in[1];
  const int*   isz      = (const int*)d_in[2];
  const float* Wq = (const float*)d_in[3];
  const float* bq = (const float*)d_in[4];
  const float* Wk = (const float*)d_in[5];
  const float* bk = (const float*)d_in[6];
  const float* Wv = (const float*)d_in[7];
  const float* bv = (const float*)d_in[8];
  const float* Wo = (const float*)d_in[9];
  const float* bo = (const float*)d_in[10];
  const float* gamma = (const float*)d_in[11];
  const float* beta  = (const float*)d_in[12];
  const float* dist_emb = (const float*)d_in[13];

  float* out = (float*)d_out;                   // (B,N,D) = 8192*768 f32
  float* att = out + (size_t)8192 * 768;        // (B,H,N,N) f32

  char* w = (char*)d_ws;
  unsigned short* ppk = (unsigned short*)w;     w += 8192 * 2;
  unsigned short* x = (unsigned short*)w;       w += (size_t)8192 * 768 * 2;
  unsigned short* wcat = (unsigned short*)w;    w += (size_t)2304 * 768 * 2;
  unsigned short* wo = (unsigned short*)w;      w += (size_t)768 * 768 * 2;
  float* bcat = (float*)w;                      w += 2304 * 4;
  unsigned short* qkv = (unsigned short*)w;     w += (size_t)8192 * 2304 * 2;
  unsigned short* attnout = (unsigned short*)w; w += (size_t)8192 * 768 * 2;

  pxpy_kernel<<<32, 256, 0, stream>>>(boxes, isz, ppk);
  ln_kernel<<<8192, 256, 0, stream>>>(features, gamma, beta, x);
  wprep_kernel<<<9216, 256, 0, stream>>>(Wq, Wk, Wv, Wo, bq, bk, bv, wcat, wo, bcat);
  gemm_bt<false><<<dim3(64, 18), 256, 0, stream>>>(x, wcat, bcat, qkv, 768, 2304);
  attn_fused<<<1536, 256, 0, stream>>>(qkv, ppk, dist_emb, att, attnout);
  gemm_bt<true><<<dim3(64, 6), 256, 0, stream>>>(attnout, wo, bo, out, 768, 768);
}